// Round 4
// baseline (41.898 us; speedup 1.0000x reference)
//
#include <hip/hip_runtime.h>

// KGather: out[n,p,t,:,:] = r_weight[n,p,t] * k[n, r_idx[n,p,t], :, :]
// Shapes: r_idx (16,49,8) int, r_weight (16,49,8) f32, k (16,49,64,128) f32
// out (16,49,8,64,128) f32.  Pure memory-bound gather+scale.
//
// Round 4: A/B experiment — identical to round 3 EXCEPT regular stores
// instead of __builtin_nontemporal_store. Rationale: out (205.5 MB) + k
// (25.7 MB) fit in the 256 MB Infinity Cache; timed graph replays rewrite
// the same output lines every iteration. Write-back stores may be absorbed
// by LLC (lines overwritten before eviction -> HBM write traffic collapses),
// whereas NT bypasses all cache levels and pins us to HBM write bandwidth.
// XCD-chunked swizzle retained (each XCD's read set = 3.2 MB < 4 MiB L2).

typedef float f32x4 __attribute__((ext_vector_type(4)));

constexpr int N    = 16;
constexpr int P2   = 49;
constexpr int TOPK = 8;
constexpr int W2   = 64;
constexpr int CK   = 128;
constexpr int WIN  = W2 * CK;      // 8192 floats = 32 KB per window
constexpr int WINV = WIN / 4;      // 2048 float4 per window
constexpr int NXCD = 8;
constexpr int NWG  = N * P2 * TOPK;        // 6272, divisible by 8
constexpr int CPX  = NWG / NXCD;           // 784 blocks per XCD chunk

__global__ __launch_bounds__(256) void kgather_kernel(
    const int*   __restrict__ r_idx,
    const float* __restrict__ r_weight,
    const float* __restrict__ k,
    float*       __restrict__ out)
{
    // XCD-chunked swizzle: launched id B runs on XCD B%8 (HW round-robin);
    // give XCD x the contiguous logical range [x*CPX, (x+1)*CPX).
    const int b  = (blockIdx.x % NXCD) * CPX + blockIdx.x / NXCD;

    const int np = b / TOPK;             // n*P2 + p
    const int n  = np / P2;

    const int   idx = r_idx[b];          // routed region index in [0, P2)
    const float w   = r_weight[b];

    const f32x4* __restrict__ src =
        reinterpret_cast<const f32x4*>(k + (size_t)(n * P2 + idx) * WIN);
    f32x4* __restrict__ dst =
        reinterpret_cast<f32x4*>(out + (size_t)b * WIN);

    #pragma unroll
    for (int i = threadIdx.x; i < WINV; i += 256) {
        f32x4 v = src[i] * w;
        dst[i] = v;
    }
}

extern "C" void kernel_launch(void* const* d_in, const int* in_sizes, int n_in,
                              void* d_out, int out_size, void* d_ws, size_t ws_size,
                              hipStream_t stream) {
    const int*   r_idx    = (const int*)  d_in[0];
    const float* r_weight = (const float*)d_in[1];
    const float* k        = (const float*)d_in[2];
    float*       out      = (float*)d_out;

    kgather_kernel<<<NWG, 256, 0, stream>>>(r_idx, r_weight, k, out);
}

// Round 5
// 40.142 us; speedup vs baseline: 1.0437x; 1.0437x over previous
//
#include <hip/hip_runtime.h>

// KGather: out[n,p,t,:,:] = r_weight[n,p,t] * k[n, r_idx[n,p,t], :, :]
// Shapes: r_idx (16,49,8) int, r_weight (16,49,8) f32, k (16,49,64,128) f32
// out (16,49,8,64,128) f32.  Pure memory-bound gather+scale.
//
// Round 5: round-3 base (NT stores + XCD-chunked swizzle, 40.0 us) plus
// explicit load/store batching: load all 8 float4 per thread into registers
// (8-deep read MLP), then scale + NT-store all 8 as one write burst. Removes
// any load->store latency leakage from the write-issue stream.
// A/B history: NT vs regular stores = 40.0 vs 41.9 us (NT kept);
// LLC does NOT absorb the replayed 205 MB write stream (H2 refuted).

typedef float f32x4 __attribute__((ext_vector_type(4)));

constexpr int N    = 16;
constexpr int P2   = 49;
constexpr int TOPK = 8;
constexpr int W2   = 64;
constexpr int CK   = 128;
constexpr int WIN  = W2 * CK;      // 8192 floats = 32 KB per window
constexpr int WINV = WIN / 4;      // 2048 float4 per window
constexpr int ITER = WINV / 256;   // 8 float4 per thread
constexpr int NXCD = 8;
constexpr int NWG  = N * P2 * TOPK;        // 6272, divisible by 8
constexpr int CPX  = NWG / NXCD;           // 784 blocks per XCD chunk

__global__ __launch_bounds__(256) void kgather_kernel(
    const int*   __restrict__ r_idx,
    const float* __restrict__ r_weight,
    const float* __restrict__ k,
    float*       __restrict__ out)
{
    // XCD-chunked swizzle: launched id B runs on XCD B%8 (HW round-robin);
    // give XCD x the contiguous logical range [x*CPX, (x+1)*CPX).
    // => XCD x reads exactly n in {2x, 2x+1}: 3.2 MB < 4 MiB L2.
    const int b  = (blockIdx.x % NXCD) * CPX + blockIdx.x / NXCD;

    const int np = b / TOPK;             // n*P2 + p
    const int n  = np / P2;

    const int   idx = r_idx[b];          // routed region index in [0, P2)
    const float w   = r_weight[b];

    const f32x4* __restrict__ src =
        reinterpret_cast<const f32x4*>(k + (size_t)(n * P2 + idx) * WIN);
    f32x4* __restrict__ dst =
        reinterpret_cast<f32x4*>(out + (size_t)b * WIN);

    f32x4 v[ITER];
    #pragma unroll
    for (int j = 0; j < ITER; ++j)
        v[j] = src[threadIdx.x + j * 256];

    #pragma unroll
    for (int j = 0; j < ITER; ++j) {
        f32x4 s = v[j] * w;
        __builtin_nontemporal_store(s, &dst[threadIdx.x + j * 256]);
    }
}

extern "C" void kernel_launch(void* const* d_in, const int* in_sizes, int n_in,
                              void* d_out, int out_size, void* d_ws, size_t ws_size,
                              hipStream_t stream) {
    const int*   r_idx    = (const int*)  d_in[0];
    const float* r_weight = (const float*)d_in[1];
    const float* k        = (const float*)d_in[2];
    float*       out      = (float*)d_out;

    kgather_kernel<<<NWG, 256, 0, stream>>>(r_idx, r_weight, k, out);
}